// Round 8
// baseline (518.121 us; speedup 1.0000x reference)
//
#include <hip/hip_runtime.h>

// Problem constants
#define NB 128
#define NL 1024
#define NE 512
#define NA 512
#define ND 512

typedef __attribute__((ext_vector_type(8))) short short8;
typedef __attribute__((ext_vector_type(4))) float f32x4;

static __device__ __forceinline__ unsigned short f2bf(float f) {
  unsigned int u = __float_as_uint(f);
  u += 0x7FFF + ((u >> 16) & 1);   // round-to-nearest-even
  return (unsigned short)(u >> 16);
}

// async global->LDS, 16B per lane (wave-uniform LDS base + lane*16)
static __device__ __forceinline__ void async_cp16(const void* g, void* l) {
  __builtin_amdgcn_global_load_lds(
      (const __attribute__((address_space(1))) void*)g,
      (__attribute__((address_space(3))) void*)l, 16, 0, 0);
}

#define FENCE asm volatile("" ::: "memory")

// ---------------------------------------------------------------------------
// Kernel 1: blocks 0..63 pack W_enc -> bf16 MFMA B-fragment order;
// blocks 64..191: att2[b][a] = dec[b]@W_dec[:,a] + b_dec[a] + b_enc[a].
// Bpack: [ki=0..15][nf=0..31][lane=0..63][j=0..7]
__global__ void k_prep(const float* __restrict__ W_enc,
                       unsigned short* __restrict__ Bpack,
                       const float* __restrict__ dec,
                       const float* __restrict__ Wdec,
                       const float* __restrict__ b_enc,
                       const float* __restrict__ b_dec,
                       float* __restrict__ att2) {
  int blk = blockIdx.x;
  int tid = threadIdx.x;  // 512
  if (blk < 64) {
    int t = blk * 512 + tid;
    int lane = t & 63;
    int rest = t >> 6;
    int nf = rest & 31;
    int ki = rest >> 5;
    int col = nf * 16 + (lane & 15);
    int kbase = ki * 32 + (lane >> 4) * 8;
    short8 v;
#pragma unroll
    for (int j = 0; j < 8; ++j)
      v[j] = (short)f2bf(W_enc[(kbase + j) * NA + col]);
    *reinterpret_cast<short8*>(Bpack + (long)t * 8) = v;
  } else {
    int b = blk - 64;
    int a = tid;
    float acc = b_enc[a] + b_dec[a];
    const float* drow = dec + b * ND;
#pragma unroll 4
    for (int d = 0; d < ND; ++d)
      acc += drow[d] * Wdec[d * NA + a];
    att2[b * NA + a] = acc;
  }
}

// ---------------------------------------------------------------------------
// Kernel 2: fused persistent scores+online-softmax+weighted-sum.
// 256 blocks (blk -> batch blk/2, rows [blk*512, +512)), 512 thr (8 waves),
// 8 tiles of 64 rows, FULLY UNROLLED.
// LDS: A row-major bf16 [64][512] w/ XOR swizzle (0..64K);
//      B ring 3 x 32KB (65536 + slot*32768), per-wave-private slices.
// Per K-step: issue B chunk (slot +2 ahead, per-wave counted vmcnt, never 0)
// + 2 fA global loads (steps 0..7). Epilogue: barrier (RACE FIX: all waves'
// S=15 B-reads must finish before slot T%3 is reused) -> scores -> cross-wave
// reduce -> online m/Z -> PV from bf16 A-tile in LDS.
__global__ __attribute__((amdgpu_waves_per_eu(2, 2))) void
__launch_bounds__(512) k_main(
    const float* __restrict__ enc, const unsigned short* __restrict__ Bpack,
    const float* __restrict__ att2g, const float* __restrict__ wfull,
    float* __restrict__ attg, float* __restrict__ og,
    float* __restrict__ mzg) {
  extern __shared__ char smem[];
  const int t = threadIdx.x;
  const int lane = t & 63;
  const int wave = t >> 6;
  const int l15 = lane & 15;
  const int lq = lane >> 4;
  const int blk = blockIdx.x;       // 0..255
  const int batch = blk >> 1;
  const long rowbase = (long)blk * 512;
  const int rhalf = (t >= 256) ? 32 : 0;
  const int e2 = (t & 255) * 2;

  float a2r[4], wfr[4];
#pragma unroll
  for (int cf = 0; cf < 4; ++cf) {
    a2r[cf] = att2g[batch * NA + wave * 64 + cf * 16 + l15];
    wfr[cf] = wfull[wave * 64 + cf * 16 + l15];
  }

  float4 fA[16];
  float att_r[8];
  float m_run = -__builtin_huge_valf();
  float Zrun = 0.f;
  float o0 = 0.f, o1 = 0.f;

#define B_ISSUE(C, SLOT)                                                      \
  {                                                                           \
    _Pragma("unroll") for (int cf = 0; cf < 4; ++cf) {                        \
      const unsigned short* bsrc =                                            \
          Bpack + (((long)(C)*32 + wave * 4 + cf) * 64 + lane) * 8;           \
      char* bdst =                                                            \
          smem + 65536 + (SLOT)*32768 + wave * 4096 + cf * 1024 + lane * 16;  \
      async_cp16(bsrc, bdst);                                                 \
    }                                                                         \
  }

#define A_LOAD_STEP(TN, S)                                                    \
  {                                                                           \
    int fr = (S)*8 + wave;                                                    \
    int row = ((fr >> 4) << 4) + l15;                                         \
    int k0 = ((fr & 15) << 5) + (lq << 3);                                    \
    const float4* p = reinterpret_cast<const float4*>(                        \
        enc + ((rowbase + (TN)*64 + row) << 9) + k0);                         \
    fA[(S)*2] = p[0];                                                         \
    fA[(S)*2 + 1] = p[1];                                                     \
  }

#define A_WRITE_ALL()                                                         \
  {                                                                           \
    _Pragma("unroll") for (int s2 = 0; s2 < 8; ++s2) {                        \
      int fr = s2 * 8 + wave;                                                 \
      int row = ((fr >> 4) << 4) + l15;                                       \
      int k0 = ((fr & 15) << 5) + (lq << 3);                                  \
      float4 x0 = fA[s2 * 2], x1 = fA[s2 * 2 + 1];                            \
      short8 o;                                                               \
      o[0] = (short)f2bf(x0.x); o[1] = (short)f2bf(x0.y);                     \
      o[2] = (short)f2bf(x0.z); o[3] = (short)f2bf(x0.w);                     \
      o[4] = (short)f2bf(x1.x); o[5] = (short)f2bf(x1.y);                     \
      o[6] = (short)f2bf(x1.z); o[7] = (short)f2bf(x1.w);                     \
      int byt = (row * 1024 + k0 * 2) ^ ((row & 7) << 4);                     \
      *reinterpret_cast<short8*>(smem + byt) = o;                             \
    }                                                                         \
  }

  // ---- prologue: tile 0 ----
  B_ISSUE(0, 0);
  B_ISSUE(1, 1);
  FENCE;
#pragma unroll
  for (int s = 0; s < 8; ++s) A_LOAD_STEP(0, s);
  A_WRITE_ALL();      // compiler waits fA; B0/B1 drained by barrier below
  __syncthreads();

  f32x4 acc[4][4];
#pragma unroll
  for (int rt = 0; rt < 4; ++rt)
#pragma unroll
    for (int cf = 0; cf < 4; ++cf) acc[rt][cf] = (f32x4){0.f, 0.f, 0.f, 0.f};

#pragma unroll
  for (int T = 0; T < 8; ++T) {
#pragma unroll
    for (int S = 0; S < 16; ++S) {
      if (T < 7 || S < 14) B_ISSUE((S + 2) & 15, (16 * T + S + 2) % 3);
      FENCE;
      if (T < 7 && S < 8) A_LOAD_STEP(T + 1, S);
      if (S >= 2) {
        asm volatile("s_waitcnt vmcnt(%0)" ::"i"(
            (T < 7) ? (S <= 7 ? 14 : S == 8 ? 12 : S == 9 ? 10 : 8)
                    : (S <= 13 ? 8 : S == 14 ? 4 : 0))
                     : "memory");
      }
      const char* bbase =
          smem + 65536 + ((16 * T + S) % 3) * 32768 + wave * 4096 + lane * 16;
      short8 bv0 = *reinterpret_cast<const short8*>(bbase);
      short8 bv1 = *reinterpret_cast<const short8*>(bbase + 1024);
      short8 bv2 = *reinterpret_cast<const short8*>(bbase + 2048);
      short8 bv3 = *reinterpret_cast<const short8*>(bbase + 3072);
      short8 av0, av1, av2, av3;
      {
        int abase = (l15 * 1024 + S * 64 + lq * 16) ^ ((l15 & 7) << 4);
        av0 = *reinterpret_cast<const short8*>(smem + abase);
        av1 = *reinterpret_cast<const short8*>(smem + abase + 16384);
        av2 = *reinterpret_cast<const short8*>(smem + abase + 32768);
        av3 = *reinterpret_cast<const short8*>(smem + abase + 49152);
      }
      acc[0][0] = __builtin_amdgcn_mfma_f32_16x16x32_bf16(av0, bv0, acc[0][0], 0, 0, 0);
      acc[0][1] = __builtin_amdgcn_mfma_f32_16x16x32_bf16(av0, bv1, acc[0][1], 0, 0, 0);
      acc[0][2] = __builtin_amdgcn_mfma_f32_16x16x32_bf16(av0, bv2, acc[0][2], 0, 0, 0);
      acc[0][3] = __builtin_amdgcn_mfma_f32_16x16x32_bf16(av0, bv3, acc[0][3], 0, 0, 0);
      acc[1][0] = __builtin_amdgcn_mfma_f32_16x16x32_bf16(av1, bv0, acc[1][0], 0, 0, 0);
      acc[1][1] = __builtin_amdgcn_mfma_f32_16x16x32_bf16(av1, bv1, acc[1][1], 0, 0, 0);
      acc[1][2] = __builtin_amdgcn_mfma_f32_16x16x32_bf16(av1, bv2, acc[1][2], 0, 0, 0);
      acc[1][3] = __builtin_amdgcn_mfma_f32_16x16x32_bf16(av1, bv3, acc[1][3], 0, 0, 0);
      acc[2][0] = __builtin_amdgcn_mfma_f32_16x16x32_bf16(av2, bv0, acc[2][0], 0, 0, 0);
      acc[2][1] = __builtin_amdgcn_mfma_f32_16x16x32_bf16(av2, bv1, acc[2][1], 0, 0, 0);
      acc[2][2] = __builtin_amdgcn_mfma_f32_16x16x32_bf16(av2, bv2, acc[2][2], 0, 0, 0);
      acc[2][3] = __builtin_amdgcn_mfma_f32_16x16x32_bf16(av2, bv3, acc[2][3], 0, 0, 0);
      acc[3][0] = __builtin_amdgcn_mfma_f32_16x16x32_bf16(av3, bv0, acc[3][0], 0, 0, 0);
      acc[3][1] = __builtin_amdgcn_mfma_f32_16x16x32_bf16(av3, bv1, acc[3][1], 0, 0, 0);
      acc[3][2] = __builtin_amdgcn_mfma_f32_16x16x32_bf16(av3, bv2, acc[3][2], 0, 0, 0);
      acc[3][3] = __builtin_amdgcn_mfma_f32_16x16x32_bf16(av3, bv3, acc[3][3], 0, 0, 0);
    }

    // ---- tile epilogue: scores -> online softmax -> PV ----
    {
      // RACE FIX: slot T%3 is about to be reused for red/plds. Every wave
      // must have completed its S=15 ds_reads of that slot first.
      __syncthreads();
      float px[4][4];
#pragma unroll
      for (int rt = 0; rt < 4; ++rt)
#pragma unroll
        for (int r = 0; r < 4; ++r) px[rt][r] = 0.f;
#pragma unroll
      for (int cf = 0; cf < 4; ++cf) {
        float a2 = a2r[cf], w = wfr[cf];
#pragma unroll
        for (int rt = 0; rt < 4; ++rt)
#pragma unroll
          for (int r = 0; r < 4; ++r) {
            float v = acc[rt][cf][r] + a2;
            px[rt][r] += fmaxf(v, 0.f) * w;
          }
      }
#pragma unroll
      for (int rt = 0; rt < 4; ++rt)
#pragma unroll
        for (int r = 0; r < 4; ++r) {
          float p_ = px[rt][r];
          p_ += __shfl_xor(p_, 1);
          p_ += __shfl_xor(p_, 2);
          p_ += __shfl_xor(p_, 4);
          p_ += __shfl_xor(p_, 8);
          px[rt][r] = p_;
        }
      float* red = (float*)(smem + 65536 + ((16 * T + 15) % 3) * 32768);
      float* plds = red + 512;
      if (l15 == 0) {
#pragma unroll
        for (int rt = 0; rt < 4; ++rt)
#pragma unroll
          for (int r = 0; r < 4; ++r)
            red[wave * 64 + rt * 16 + lq * 4 + r] = px[rt][r];
      }
      __syncthreads();
      float sc = 0.f;
#pragma unroll
      for (int w8 = 0; w8 < 8; ++w8) sc += red[w8 * 64 + lane];
      att_r[T] = sc;
      float tmax = sc;
#pragma unroll
      for (int off = 1; off < 64; off <<= 1)
        tmax = fmaxf(tmax, __shfl_xor(tmax, off));
      float m_new = fmaxf(m_run, tmax);
      float scale = expf(m_run - m_new);
      float pv_ = expf(sc - m_new);
      float psum = pv_;
#pragma unroll
      for (int off = 1; off < 64; off <<= 1) psum += __shfl_xor(psum, off);
      Zrun = Zrun * scale + psum;
      m_run = m_new;
      plds[lane] = pv_;   // all waves write identical values; benign
      __syncthreads();
      o0 *= scale;
      o1 *= scale;
#pragma unroll
      for (int i = 0; i < 32; ++i) {
        int row = rhalf + i;
        float pw = plds[row];
        int byt = (row * 1024 + e2 * 2) ^ ((row & 7) << 4);
        unsigned u = *reinterpret_cast<const unsigned*>(smem + byt);
        o0 += pw * __uint_as_float(u << 16);
        o1 += pw * __uint_as_float(u & 0xffff0000u);
      }
#pragma unroll
      for (int rt = 0; rt < 4; ++rt)
#pragma unroll
        for (int cf = 0; cf < 4; ++cf)
          acc[rt][cf] = (f32x4){0.f, 0.f, 0.f, 0.f};
    }
    if (T < 7) {
      __syncthreads();   // all waves done reading A (PV) before overwrite
      A_WRITE_ALL();     // stage tile T+1's A
      __syncthreads();
    }
  }
#undef B_ISSUE
#undef A_LOAD_STEP
#undef A_WRITE_ALL

  // ---- final outputs ----
  __syncthreads();
  float2* xch = (float2*)smem;   // A region is dead now
  if (t >= 256) xch[t - 256] = make_float2(o0, o1);
  __syncthreads();
  if (t < 256) {
    float2 hi = xch[t];
    float2 res = make_float2(o0 + hi.x, o1 + hi.y);
    *reinterpret_cast<float2*>(og + blk * 512 + e2) = res;
  }
  if (t < 64) {
#pragma unroll
    for (int T = 0; T < 8; ++T) attg[blk * 512 + T * 64 + t] = att_r[T];
  }
  if (t == 0) {
    mzg[blk * 2] = m_run;
    mzg[blk * 2 + 1] = Zrun;
  }
}

// ---------------------------------------------------------------------------
// Kernel 3: merge the two half-batch (m,Z,o) states; emit weighted + alpha.
__global__ void k_final(const float* __restrict__ attg,
                        const float* __restrict__ og,
                        const float* __restrict__ mzg,
                        float* __restrict__ weighted,
                        float* __restrict__ alpha) {
  int b = blockIdx.x;   // 0..127
  int t = threadIdx.x;  // 512
  float m0 = mzg[(2 * b) * 2], z0 = mzg[(2 * b) * 2 + 1];
  float m1 = mzg[(2 * b + 1) * 2], z1 = mzg[(2 * b + 1) * 2 + 1];
  float m = fmaxf(m0, m1);
  float s0 = expf(m0 - m), s1 = expf(m1 - m);
  float inv = 1.f / (z0 * s0 + z1 * s1);
  weighted[b * NE + t] =
      (s0 * og[(2 * b) * 512 + t] + s1 * og[(2 * b + 1) * 512 + t]) * inv;
  float a0 = attg[(2 * b) * 512 + t];
  float a1 = attg[(2 * b + 1) * 512 + t];
  alpha[b * NL + t] = expf(a0 - m) * inv;
  alpha[b * NL + 512 + t] = expf(a1 - m) * inv;
}

// ---------------------------------------------------------------------------
extern "C" void kernel_launch(void* const* d_in, const int* in_sizes, int n_in,
                              void* d_out, int out_size, void* d_ws, size_t ws_size,
                              hipStream_t stream) {
  const float* enc    = (const float*)d_in[0];  // [B,L,E]
  const float* dec    = (const float*)d_in[1];  // [B,D]
  const float* W_enc  = (const float*)d_in[2];  // [E,A]
  const float* b_enc  = (const float*)d_in[3];  // [A]
  const float* W_dec  = (const float*)d_in[4];  // [D,A]
  const float* b_dec  = (const float*)d_in[5];  // [A]
  const float* W_full = (const float*)d_in[6];  // [A]
  // d_in[7] = b_full: cancels in softmax, unused.

  float* out = (float*)d_out;
  float* weighted = out;                 // [B,E]
  float* alpha = out + NB * NE;          // [B,L]

  char* ws = (char*)d_ws;
  float* att2          = (float*)ws;                           // 256 KB
  unsigned short* Bpk  = (unsigned short*)(ws + (256 << 10));  // 512 KB
  float* attg          = (float*)(ws + (768 << 10));           // 512 KB
  float* og            = (float*)(ws + (1280 << 10));          // 512 KB
  float* mzg           = (float*)(ws + (1792 << 10));          // 2 KB

  hipLaunchKernelGGL(k_prep, dim3(192), dim3(512), 0, stream,
                     W_enc, Bpk, dec, W_dec, b_enc, b_dec, att2);
  hipLaunchKernelGGL(k_main, dim3(256), dim3(512), 163840, stream,
                     enc, Bpk, att2, W_full, attg, og, mzg);
  hipLaunchKernelGGL(k_final, dim3(NB), dim3(512), 0, stream,
                     attg, og, mzg, weighted, alpha);
}

// Round 9
// 145.008 us; speedup vs baseline: 3.5730x; 3.5730x over previous
//
#include <hip/hip_runtime.h>

// Problem constants
#define NB 128
#define NL 1024
#define NE 512
#define NA 512
#define ND 512

typedef __attribute__((ext_vector_type(8))) short short8;
typedef __attribute__((ext_vector_type(4))) float f32x4;

static __device__ __forceinline__ unsigned short f2bf(float f) {
  unsigned int u = __float_as_uint(f);
  u += 0x7FFF + ((u >> 16) & 1);   // round-to-nearest-even
  return (unsigned short)(u >> 16);
}

// ---------------------------------------------------------------------------
// Kernel 1: blocks 0..63 pack W_enc -> bf16 MFMA B-fragment order;
// blocks 64..191: att2[b][a] = dec[b]@W_dec[:,a] + b_dec[a] + b_enc[a].
// Bpack: [ki=0..15][nf=0..31][lane=0..63][j=0..7]
//   lane l holds B[k][n], k = ki*32 + (l>>4)*8 + j, n = nf*16 + (l&15)
__global__ void k_prep(const float* __restrict__ W_enc,
                       unsigned short* __restrict__ Bpack,
                       const float* __restrict__ dec,
                       const float* __restrict__ Wdec,
                       const float* __restrict__ b_enc,
                       const float* __restrict__ b_dec,
                       float* __restrict__ att2) {
  int blk = blockIdx.x;
  int tid = threadIdx.x;  // 512
  if (blk < 64) {
    int t = blk * 512 + tid;
    int lane = t & 63;
    int rest = t >> 6;
    int nf = rest & 31;
    int ki = rest >> 5;
    int col = nf * 16 + (lane & 15);
    int kbase = ki * 32 + (lane >> 4) * 8;
    short8 v;
#pragma unroll
    for (int j = 0; j < 8; ++j)
      v[j] = (short)f2bf(W_enc[(kbase + j) * NA + col]);
    *reinterpret_cast<short8*>(Bpack + (long)t * 8) = v;
  } else {
    int b = blk - 64;
    int a = tid;
    float acc = b_enc[a] + b_dec[a];
    const float* drow = dec + b * ND;
#pragma unroll 4
    for (int d = 0; d < ND; ++d)
      acc += drow[d] * Wdec[d * NA + a];
    att2[b * NA + a] = acc;
  }
}

// ---------------------------------------------------------------------------
// Kernel 2: fused scores + per-block softmax-partial + PV. NON-persistent:
// 2048 blocks x 64 rows, 512 thr (8 waves). Small register state
// (acc[4][4]=64 + bv[4]+av[4]=32, ~120 total, cap 128 via waves_per_eu(4))
// -> 2 blocks/CU, 16 waves/CU: TLP hides A-staging + B-L2 latency.
// A: LDS bf16 [64][512] XOR-swizzled, staged once (coalesced). B: per-ki
// direct L2->reg loads (Bpack is L2-resident; compiler pipelines the
// unrolled loop). Epilogue: relu(acc+att2)*W_full -> per-row score ->
// per-block (m, Z, o-partial) to global; k_final merges 16 blocks/batch.
__global__ __attribute__((amdgpu_waves_per_eu(4))) __launch_bounds__(512)
void k_main(const float* __restrict__ enc,
            const unsigned short* __restrict__ Bpack,
            const float* __restrict__ att2g, const float* __restrict__ wfull,
            float* __restrict__ attg, float* __restrict__ ogp,
            float* __restrict__ mzg) {
  extern __shared__ char smem[];       // 64KB A | 2KB red | 256B p
  const int t = threadIdx.x;
  const int lane = t & 63;
  const int wave = t >> 6;
  const int l15 = lane & 15;
  const int lq = lane >> 4;
  const int blk = blockIdx.x;          // 0..2047
  const int batch = blk >> 4;          // 16 blocks per batch
  const long row0 = (long)blk * 64;

  // ---- stage A: 64 rows x 512 f fp32 -> bf16 LDS, XOR swizzle ----
  {
    const float4* src = reinterpret_cast<const float4*>(enc + row0 * NE);
#pragma unroll
    for (int j = 0; j < 16; ++j) {
      int idx = j * 512 + t;           // tile has 8192 float4s
      float4 x = src[idx];
      int row = idx >> 7;              // 128 float4 per row
      int cb = (idx & 127) * 8;        // byte offset within bf16 row
      short4 o;
      o.x = (short)f2bf(x.x);
      o.y = (short)f2bf(x.y);
      o.z = (short)f2bf(x.z);
      o.w = (short)f2bf(x.w);
      int byt = (row * 1024 + cb) ^ ((row & 7) << 4);
      *reinterpret_cast<short4*>(smem + byt) = o;
    }
  }
  __syncthreads();

  // ---- K-loop: wave covers cols [wave*64, +64), all 64 rows ----
  f32x4 acc[4][4];
#pragma unroll
  for (int rt = 0; rt < 4; ++rt)
#pragma unroll
    for (int cf = 0; cf < 4; ++cf) acc[rt][cf] = (f32x4){0.f, 0.f, 0.f, 0.f};

  const short8* bp = reinterpret_cast<const short8*>(Bpack);
#pragma unroll
  for (int ki = 0; ki < 16; ++ki) {
    short8 bv[4], av[4];
#pragma unroll
    for (int cf = 0; cf < 4; ++cf)
      bv[cf] = bp[((ki * 32) + wave * 4 + cf) * 64 + lane];
#pragma unroll
    for (int rt = 0; rt < 4; ++rt) {
      int row = rt * 16 + l15;
      int byt = (row * 1024 + ki * 64 + lq * 16) ^ ((row & 7) << 4);
      av[rt] = *reinterpret_cast<const short8*>(smem + byt);
    }
#pragma unroll
    for (int rt = 0; rt < 4; ++rt)
#pragma unroll
      for (int cf = 0; cf < 4; ++cf)
        acc[rt][cf] = __builtin_amdgcn_mfma_f32_16x16x32_bf16(
            av[rt], bv[cf], acc[rt][cf], 0, 0, 0);
  }

  // ---- epilogue: scores -> m,Z,p -> PV partial ----
  float a2r[4], wfr[4];
#pragma unroll
  for (int cf = 0; cf < 4; ++cf) {
    int col = wave * 64 + cf * 16 + l15;
    a2r[cf] = att2g[batch * NA + col];
    wfr[cf] = wfull[col];
  }
  float px[4][4];
#pragma unroll
  for (int rt = 0; rt < 4; ++rt)
#pragma unroll
    for (int r = 0; r < 4; ++r) px[rt][r] = 0.f;
#pragma unroll
  for (int cf = 0; cf < 4; ++cf) {
#pragma unroll
    for (int rt = 0; rt < 4; ++rt)
#pragma unroll
      for (int r = 0; r < 4; ++r) {
        float v = acc[rt][cf][r] + a2r[cf];
        px[rt][r] += fmaxf(v, 0.f) * wfr[cf];
      }
  }
#pragma unroll
  for (int rt = 0; rt < 4; ++rt)
#pragma unroll
    for (int r = 0; r < 4; ++r) {
      float p_ = px[rt][r];
      p_ += __shfl_xor(p_, 1);
      p_ += __shfl_xor(p_, 2);
      p_ += __shfl_xor(p_, 4);
      p_ += __shfl_xor(p_, 8);
      px[rt][r] = p_;
    }
  float* red = (float*)(smem + 65536);     // 512 f
  float* pl = (float*)(smem + 65536 + 2048);  // 64 f
  if (l15 == 0) {
#pragma unroll
    for (int rt = 0; rt < 4; ++rt)
#pragma unroll
      for (int r = 0; r < 4; ++r)
        red[wave * 64 + rt * 16 + lq * 4 + r] = px[rt][r];
  }
  __syncthreads();
  // every wave computes the full 64-row score vector (redundant, cheap)
  float sc = 0.f;
#pragma unroll
  for (int w8 = 0; w8 < 8; ++w8) sc += red[w8 * 64 + lane];
  if (t < 64) attg[blk * 64 + t] = sc;    // raw scores for alpha later
  float m = sc;
#pragma unroll
  for (int off = 1; off < 64; off <<= 1) m = fmaxf(m, __shfl_xor(m, off));
  float p = expf(sc - m);
  float Z = p;
#pragma unroll
  for (int off = 1; off < 64; off <<= 1) Z += __shfl_xor(Z, off);
  if (t < 64) pl[t] = p;
  __syncthreads();

  // PV: o[e] = sum_row p[row] * A_bf16[row][e]; rows split across halves
  {
    int half = t >> 8;              // 0: rows 0..31, 1: rows 32..63
    int e = (t & 255) * 2;          // col pair
    float o0 = 0.f, o1 = 0.f;
#pragma unroll
    for (int i = 0; i < 32; ++i) {
      int row = half * 32 + i;
      float pw = pl[row];
      int byt = (row * 1024 + e * 2) ^ ((row & 7) << 4);
      unsigned u = *reinterpret_cast<const unsigned*>(smem + byt);
      o0 += pw * __uint_as_float(u << 16);
      o1 += pw * __uint_as_float(u & 0xffff0000u);
    }
    __syncthreads();
    float2* xch = (float2*)red;     // red is dead; reuse for half-merge
    if (half) xch[t - 256] = make_float2(o0, o1);
    __syncthreads();
    if (!half) {
      float2 hv = xch[t];
      *reinterpret_cast<float2*>(ogp + (long)blk * 512 + e) =
          make_float2(o0 + hv.x, o1 + hv.y);
    }
    if (t == 0) {
      mzg[blk * 2] = m;
      mzg[blk * 2 + 1] = Z;
    }
  }
}

// ---------------------------------------------------------------------------
// Kernel 3: merge 16 per-block (m,Z,o) partials per batch; emit weighted+alpha.
__global__ void k_final(const float* __restrict__ attg,
                        const float* __restrict__ ogp,
                        const float* __restrict__ mzg,
                        float* __restrict__ weighted,
                        float* __restrict__ alpha) {
  int b = blockIdx.x;   // 0..127
  int t = threadIdx.x;  // 512
  float mv[16], zv[16];
  float m = -__builtin_huge_valf();
#pragma unroll
  for (int i = 0; i < 16; ++i) {
    mv[i] = mzg[(b * 16 + i) * 2];
    zv[i] = mzg[(b * 16 + i) * 2 + 1];
    m = fmaxf(m, mv[i]);
  }
  float Z = 0.f;
#pragma unroll
  for (int i = 0; i < 16; ++i) {
    float s = expf(mv[i] - m);
    mv[i] = s;
    Z += s * zv[i];
  }
  float inv = 1.f / Z;
  float o = 0.f;
#pragma unroll
  for (int i = 0; i < 16; ++i) o += mv[i] * ogp[((long)b * 16 + i) * 512 + t];
  weighted[b * NE + t] = o * inv;
  alpha[b * NL + t] = expf(attg[b * NL + t] - m) * inv;
  alpha[b * NL + 512 + t] = expf(attg[b * NL + 512 + t] - m) * inv;
}

// ---------------------------------------------------------------------------
extern "C" void kernel_launch(void* const* d_in, const int* in_sizes, int n_in,
                              void* d_out, int out_size, void* d_ws, size_t ws_size,
                              hipStream_t stream) {
  const float* enc    = (const float*)d_in[0];  // [B,L,E]
  const float* dec    = (const float*)d_in[1];  // [B,D]
  const float* W_enc  = (const float*)d_in[2];  // [E,A]
  const float* b_enc  = (const float*)d_in[3];  // [A]
  const float* W_dec  = (const float*)d_in[4];  // [D,A]
  const float* b_dec  = (const float*)d_in[5];  // [A]
  const float* W_full = (const float*)d_in[6];  // [A]
  // d_in[7] = b_full: cancels in softmax, unused.

  float* out = (float*)d_out;
  float* weighted = out;                 // [B,E]
  float* alpha = out + NB * NE;          // [B,L]

  char* ws = (char*)d_ws;
  float* att2          = (float*)ws;                           // 256 KB
  unsigned short* Bpk  = (unsigned short*)(ws + (256 << 10));  // 512 KB
  float* attg          = (float*)(ws + (768 << 10));           // 512 KB
  float* ogp           = (float*)(ws + (1280 << 10));          // 4 MB
  float* mzg           = (float*)(ws + (5376 << 10));          // 16 KB

  hipLaunchKernelGGL(k_prep, dim3(192), dim3(512), 0, stream,
                     W_enc, Bpk, dec, W_dec, b_enc, b_dec, att2);
  hipLaunchKernelGGL(k_main, dim3(2048), dim3(512), 67840, stream,
                     enc, Bpk, att2, W_full, attg, ogp, mzg);
  hipLaunchKernelGGL(k_final, dim3(NB), dim3(512), 0, stream,
                     attg, ogp, mzg, weighted, alpha);
}

// Round 10
// 123.713 us; speedup vs baseline: 4.1881x; 1.1721x over previous
//
#include <hip/hip_runtime.h>

// Problem constants
#define NB 128
#define NL 1024
#define NE 512
#define NA 512
#define ND 512

typedef __attribute__((ext_vector_type(8))) short short8;
typedef __attribute__((ext_vector_type(4))) float f32x4;

static __device__ __forceinline__ unsigned short f2bf(float f) {
  unsigned int u = __float_as_uint(f);
  u += 0x7FFF + ((u >> 16) & 1);   // round-to-nearest-even
  return (unsigned short)(u >> 16);
}

// ---------------------------------------------------------------------------
// Kernel 1: blocks 0..63 pack W_enc -> bf16 MFMA B-fragment order;
// blocks 64..191: att2[b][a] = dec[b]@W_dec[:,a] + b_dec[a] + b_enc[a].
// Bpack: [ki=0..15][nf=0..31][lane=0..63][j=0..7]
__global__ void k_prep(const float* __restrict__ W_enc,
                       unsigned short* __restrict__ Bpack,
                       const float* __restrict__ dec,
                       const float* __restrict__ Wdec,
                       const float* __restrict__ b_enc,
                       const float* __restrict__ b_dec,
                       float* __restrict__ att2) {
  int blk = blockIdx.x;
  int tid = threadIdx.x;  // 512
  if (blk < 64) {
    int t = blk * 512 + tid;
    int lane = t & 63;
    int rest = t >> 6;
    int nf = rest & 31;
    int ki = rest >> 5;
    int col = nf * 16 + (lane & 15);
    int kbase = ki * 32 + (lane >> 4) * 8;
    short8 v;
#pragma unroll
    for (int j = 0; j < 8; ++j)
      v[j] = (short)f2bf(W_enc[(kbase + j) * NA + col]);
    *reinterpret_cast<short8*>(Bpack + (long)t * 8) = v;
  } else {
    int b = blk - 64;
    int a = tid;
    float acc = b_enc[a] + b_dec[a];
    const float* drow = dec + b * ND;
#pragma unroll 8
    for (int d = 0; d < ND; ++d)
      acc += drow[d] * Wdec[d * NA + a];
    att2[b * NA + a] = acc;
  }
}

// ---------------------------------------------------------------------------
// Kernel 2: fused scores + per-block softmax-partial + PV. 2048 blocks x 64
// rows, 512 thr (8 waves), 2 blocks/CU. K-INTERLEAVED A-staging: prologue
// stages k[0,256) only; quarters 2,3 are loaded (2 float4/K-step, 16 VGPR
// peak) during ki0-5 and converted/written during ki2-7; one barrier before
// ki8. Halves the serialized staging time -> HBM busy under the K-loop.
// A: LDS bf16 [64][512] XOR-swizzled. B: per-ki direct L2->reg loads.
// Epilogue identical to R9 (passing): scores -> per-block (m,Z,o) partials.
__global__ __attribute__((amdgpu_waves_per_eu(4))) __launch_bounds__(512)
void k_main(const float* __restrict__ enc,
            const unsigned short* __restrict__ Bpack,
            const float* __restrict__ att2g, const float* __restrict__ wfull,
            float* __restrict__ attg, float* __restrict__ ogp,
            float* __restrict__ mzg) {
  extern __shared__ char smem[];       // 64KB A | 2KB red | 256B p
  const int t = threadIdx.x;
  const int lane = t & 63;
  const int wave = t >> 6;
  const int l15 = lane & 15;
  const int lq = lane >> 4;
  const int blk = blockIdx.x;          // 0..2047
  const int batch = blk >> 4;          // 16 blocks per batch
  const long row0 = (long)blk * 64;
  const int srow16 = t >> 4;           // 0..31 (staging row within half)
  const int scol8 = t & 15;            // staging col8

  // Staging map: chunk (Q, FI): row = FI*32 + srow16, k0 = Q*128 + scol8*8.
  // LDS dst: (row*1024 + Q*256 + scol8*16) ^ ((row&7)<<4)  [short8]
#define G_LOAD(Q, FI, GA, GB)                                                 \
  {                                                                           \
    int row = (FI)*32 + srow16;                                               \
    const float* src = enc + (row0 + row) * NE + (Q)*128 + scol8 * 8;         \
    GA = *reinterpret_cast<const float4*>(src);                               \
    GB = *reinterpret_cast<const float4*>(src + 4);                           \
  }
#define G_WRITE(Q, FI, GA, GB)                                                \
  {                                                                           \
    int row = (FI)*32 + srow16;                                               \
    short8 o;                                                                 \
    o[0] = (short)f2bf(GA.x); o[1] = (short)f2bf(GA.y);                       \
    o[2] = (short)f2bf(GA.z); o[3] = (short)f2bf(GA.w);                       \
    o[4] = (short)f2bf(GB.x); o[5] = (short)f2bf(GB.y);                       \
    o[6] = (short)f2bf(GB.z); o[7] = (short)f2bf(GB.w);                       \
    int byt = (row * 1024 + (Q)*256 + scol8 * 16) ^ ((row & 7) << 4);         \
    *reinterpret_cast<short8*>(smem + byt) = o;                               \
  }

  // ---- prologue: stage quarters 0,1 (k 0..255) ----
  {
    float4 h[8];
#pragma unroll
    for (int c = 0; c < 4; ++c) {
      int q = c >> 1;
      int row = (c & 1) * 32 + srow16;
      const float* src = enc + (row0 + row) * NE + q * 128 + scol8 * 8;
      h[c * 2] = *reinterpret_cast<const float4*>(src);
      h[c * 2 + 1] = *reinterpret_cast<const float4*>(src + 4);
    }
#pragma unroll
    for (int c = 0; c < 4; ++c) {
      int q = c >> 1;
      int row = (c & 1) * 32 + srow16;
      float4 xa = h[c * 2], xb = h[c * 2 + 1];
      short8 o;
      o[0] = (short)f2bf(xa.x); o[1] = (short)f2bf(xa.y);
      o[2] = (short)f2bf(xa.z); o[3] = (short)f2bf(xa.w);
      o[4] = (short)f2bf(xb.x); o[5] = (short)f2bf(xb.y);
      o[6] = (short)f2bf(xb.z); o[7] = (short)f2bf(xb.w);
      int byt = (row * 1024 + q * 256 + scol8 * 16) ^ ((row & 7) << 4);
      *reinterpret_cast<short8*>(smem + byt) = o;
    }
  }
  __syncthreads();

  f32x4 acc[4][4];
#pragma unroll
  for (int rt = 0; rt < 4; ++rt)
#pragma unroll
    for (int cf = 0; cf < 4; ++cf) acc[rt][cf] = (f32x4){0.f, 0.f, 0.f, 0.f};

  const short8* bp = reinterpret_cast<const short8*>(Bpack);
#define K_STEP(KI)                                                            \
  {                                                                           \
    short8 bv0 = bp[((KI)*32 + wave * 4 + 0) * 64 + lane];                    \
    short8 bv1 = bp[((KI)*32 + wave * 4 + 1) * 64 + lane];                    \
    short8 bv2 = bp[((KI)*32 + wave * 4 + 2) * 64 + lane];                    \
    short8 bv3 = bp[((KI)*32 + wave * 4 + 3) * 64 + lane];                    \
    _Pragma("unroll") for (int rt = 0; rt < 4; ++rt) {                        \
      int row = rt * 16 + l15;                                                \
      int byt = (row * 1024 + (KI)*64 + lq * 16) ^ ((row & 7) << 4);          \
      short8 av = *reinterpret_cast<const short8*>(smem + byt);               \
      acc[rt][0] = __builtin_amdgcn_mfma_f32_16x16x32_bf16(av, bv0, acc[rt][0], 0, 0, 0); \
      acc[rt][1] = __builtin_amdgcn_mfma_f32_16x16x32_bf16(av, bv1, acc[rt][1], 0, 0, 0); \
      acc[rt][2] = __builtin_amdgcn_mfma_f32_16x16x32_bf16(av, bv2, acc[rt][2], 0, 0, 0); \
      acc[rt][3] = __builtin_amdgcn_mfma_f32_16x16x32_bf16(av, bv3, acc[rt][3], 0, 0, 0); \
    }                                                                         \
  }

  {
    float4 g0, g1, g2, g3;
    G_LOAD(2, 0, g0, g1) K_STEP(0)
    G_LOAD(2, 1, g2, g3) K_STEP(1)
    G_WRITE(2, 0, g0, g1) K_STEP(2)
    G_WRITE(2, 1, g2, g3) K_STEP(3)
    G_LOAD(3, 0, g0, g1) K_STEP(4)
    G_LOAD(3, 1, g2, g3) K_STEP(5)
    G_WRITE(3, 0, g0, g1) K_STEP(6)
    G_WRITE(3, 1, g2, g3) K_STEP(7)
  }
  __syncthreads();   // quarters 2,3 staged by all waves before ki8 reads
  K_STEP(8)  K_STEP(9)  K_STEP(10) K_STEP(11)
  K_STEP(12) K_STEP(13) K_STEP(14) K_STEP(15)
#undef K_STEP
#undef G_LOAD
#undef G_WRITE

  // ---- epilogue: scores -> m,Z,p -> PV partial (identical to R9) ----
  float a2r[4], wfr[4];
#pragma unroll
  for (int cf = 0; cf < 4; ++cf) {
    int col = wave * 64 + cf * 16 + l15;
    a2r[cf] = att2g[batch * NA + col];
    wfr[cf] = wfull[col];
  }
  float px[4][4];
#pragma unroll
  for (int rt = 0; rt < 4; ++rt)
#pragma unroll
    for (int r = 0; r < 4; ++r) px[rt][r] = 0.f;
#pragma unroll
  for (int cf = 0; cf < 4; ++cf) {
#pragma unroll
    for (int rt = 0; rt < 4; ++rt)
#pragma unroll
      for (int r = 0; r < 4; ++r) {
        float v = acc[rt][cf][r] + a2r[cf];
        px[rt][r] += fmaxf(v, 0.f) * wfr[cf];
      }
  }
#pragma unroll
  for (int rt = 0; rt < 4; ++rt)
#pragma unroll
    for (int r = 0; r < 4; ++r) {
      float p_ = px[rt][r];
      p_ += __shfl_xor(p_, 1);
      p_ += __shfl_xor(p_, 2);
      p_ += __shfl_xor(p_, 4);
      p_ += __shfl_xor(p_, 8);
      px[rt][r] = p_;
    }
  float* red = (float*)(smem + 65536);        // 512 f
  float* pl = (float*)(smem + 65536 + 2048);  // 64 f
  if (l15 == 0) {
#pragma unroll
    for (int rt = 0; rt < 4; ++rt)
#pragma unroll
      for (int r = 0; r < 4; ++r)
        red[wave * 64 + rt * 16 + lq * 4 + r] = px[rt][r];
  }
  __syncthreads();
  float sc = 0.f;
#pragma unroll
  for (int w8 = 0; w8 < 8; ++w8) sc += red[w8 * 64 + lane];
  if (t < 64) attg[blk * 64 + t] = sc;
  float m = sc;
#pragma unroll
  for (int off = 1; off < 64; off <<= 1) m = fmaxf(m, __shfl_xor(m, off));
  float p = expf(sc - m);
  float Z = p;
#pragma unroll
  for (int off = 1; off < 64; off <<= 1) Z += __shfl_xor(Z, off);
  if (t < 64) pl[t] = p;
  __syncthreads();

  {
    int half = t >> 8;
    int e = (t & 255) * 2;
    float o0 = 0.f, o1 = 0.f;
#pragma unroll
    for (int i = 0; i < 32; ++i) {
      int row = half * 32 + i;
      float pw = pl[row];
      int byt = (row * 1024 + e * 2) ^ ((row & 7) << 4);
      unsigned u = *reinterpret_cast<const unsigned*>(smem + byt);
      o0 += pw * __uint_as_float(u << 16);
      o1 += pw * __uint_as_float(u & 0xffff0000u);
    }
    __syncthreads();
    float2* xch = (float2*)red;
    if (half) xch[t - 256] = make_float2(o0, o1);
    __syncthreads();
    if (!half) {
      float2 hv = xch[t];
      *reinterpret_cast<float2*>(ogp + (long)blk * 512 + e) =
          make_float2(o0 + hv.x, o1 + hv.y);
    }
    if (t == 0) {
      mzg[blk * 2] = m;
      mzg[blk * 2 + 1] = Z;
    }
  }
}

// ---------------------------------------------------------------------------
// Kernel 3: merge 16 per-block (m,Z,o) partials per batch; emit weighted+alpha.
__global__ void k_final(const float* __restrict__ attg,
                        const float* __restrict__ ogp,
                        const float* __restrict__ mzg,
                        float* __restrict__ weighted,
                        float* __restrict__ alpha) {
  int b = blockIdx.x;   // 0..127
  int t = threadIdx.x;  // 512
  float mv[16], zv[16];
  float m = -__builtin_huge_valf();
#pragma unroll
  for (int i = 0; i < 16; ++i) {
    mv[i] = mzg[(b * 16 + i) * 2];
    zv[i] = mzg[(b * 16 + i) * 2 + 1];
    m = fmaxf(m, mv[i]);
  }
  float Z = 0.f;
#pragma unroll
  for (int i = 0; i < 16; ++i) {
    float s = expf(mv[i] - m);
    mv[i] = s;
    Z += s * zv[i];
  }
  float inv = 1.f / Z;
  float o = 0.f;
#pragma unroll
  for (int i = 0; i < 16; ++i) o += mv[i] * ogp[((long)b * 16 + i) * 512 + t];
  weighted[b * NE + t] = o * inv;
  alpha[b * NL + t] = expf(attg[b * NL + t] - m) * inv;
  alpha[b * NL + 512 + t] = expf(attg[b * NL + 512 + t] - m) * inv;
}

// ---------------------------------------------------------------------------
extern "C" void kernel_launch(void* const* d_in, const int* in_sizes, int n_in,
                              void* d_out, int out_size, void* d_ws, size_t ws_size,
                              hipStream_t stream) {
  const float* enc    = (const float*)d_in[0];  // [B,L,E]
  const float* dec    = (const float*)d_in[1];  // [B,D]
  const float* W_enc  = (const float*)d_in[2];  // [E,A]
  const float* b_enc  = (const float*)d_in[3];  // [A]
  const float* W_dec  = (const float*)d_in[4];  // [D,A]
  const float* b_dec  = (const float*)d_in[5];  // [A]
  const float* W_full = (const float*)d_in[6];  // [A]
  // d_in[7] = b_full: cancels in softmax, unused.

  float* out = (float*)d_out;
  float* weighted = out;                 // [B,E]
  float* alpha = out + NB * NE;          // [B,L]

  char* ws = (char*)d_ws;
  float* att2          = (float*)ws;                           // 256 KB
  unsigned short* Bpk  = (unsigned short*)(ws + (256 << 10));  // 512 KB
  float* attg          = (float*)(ws + (768 << 10));           // 512 KB
  float* ogp           = (float*)(ws + (1280 << 10));          // 4 MB
  float* mzg           = (float*)(ws + (5376 << 10));          // 16 KB

  hipLaunchKernelGGL(k_prep, dim3(192), dim3(512), 0, stream,
                     W_enc, Bpk, dec, W_dec, b_enc, b_dec, att2);
  hipLaunchKernelGGL(k_main, dim3(2048), dim3(512), 67840, stream,
                     enc, Bpk, att2, W_full, attg, ogp, mzg);
  hipLaunchKernelGGL(k_final, dim3(NB), dim3(512), 0, stream,
                     attg, ogp, mzg, weighted, alpha);
}